// Round 4
// baseline (96.159 us; speedup 1.0000x reference)
//
#include <hip/hip_runtime.h>

// Ball query, single-dispatch brute force. B=4, N1=2048 queries, N2=8192
// keys, K=64, r=0.1.
//
// R4 rationale (ledger): R0 3-dispatch grid pipeline = 68.2us, of which
// ~40us is the harness's 256MiB workspace poison fill and ~20us is graph
// node launch/drain overhead (~5-7us/node) — the actual kernel work is only
// ~8us. Every attempt to cut node count via intra-kernel cross-block
// coordination lost: R1 fuse-by-redundancy +7.9us, R2 cg::grid.sync +232us,
// R3 agent-scope flag handshake +10.6us (per-XCD L2 non-coherence makes the
// release/acquire chain round-trip L3). Conclusion: the only way to fewer
// nodes is to need NO build phase. Brute force needs none:
//   - one wave per 2 queries (same batch), 128 chunks x 64 keys;
//   - key batch is 96KB -> L2-resident; traffic ~98MB ~= 10TB/s << L2 peak;
//   - VALU-bound: ~39cy/chunk issue, ~6.5k cy/wave, 4 waves/SIMD -> ~11us;
//   - emission is naturally in original key order (lanes ascend = index
//     ascends), so first-K semantics + first-hit padding are exact — this is
//     the inspection-verified fallback body, interleaved for 2 queries.
// No workspace use at all (poison fill is unavoidable either way).

constexpr int   K  = 64;
constexpr float R2 = 0.01f;   // 0.1^2
constexpr int   B  = 4;
constexpr int   N1 = 2048;
constexpr int   N2 = 8192;

__global__ __launch_bounds__(256) void bq_brute2_kernel(
    const float* __restrict__ query,     // [B*N1, 3]
    const float* __restrict__ key,       // [B*N2, 3]
    int* __restrict__ out)               // [B*N1, K]
{
    const int lane = threadIdx.x & 63;
    const int w    = blockIdx.x * 4 + (threadIdx.x >> 6);   // wave id 0..4095
    const int q0   = w * 2;              // even => q0,q1 never straddle a batch
    const int q1   = q0 + 1;
    const int b    = q0 >> 11;

    const float qx0 = query[q0 * 3 + 0];
    const float qy0 = query[q0 * 3 + 1];
    const float qz0 = query[q0 * 3 + 2];
    const float qx1 = query[q1 * 3 + 0];
    const float qy1 = query[q1 * 3 + 1];
    const float qz1 = query[q1 * 3 + 2];

    const float* kb = key + (size_t)b * N2 * 3;
    const unsigned long long below =
        (lane == 0) ? 0ull : (~0ull >> (64 - lane));

    int cnt0 = 0, cnt1 = 0, f0 = -1, f1 = -1;  // f*, cnt* are wave-uniform
    int* op0 = out + (size_t)q0 * K;
    int* op1 = out + (size_t)q1 * K;

    // Fixed 128-trip loop (no early break: P(>=K hits) ~ 0 at ~34 avg hits,
    // and a break would block unroll/software-pipelining of the loads).
    #pragma unroll 4
    for (int c = 0; c < N2 / 64; ++c) {
        const int j = (c << 6) + lane;
        const float x = kb[j * 3 + 0];
        const float y = kb[j * 3 + 1];
        const float z = kb[j * 3 + 2];

        {   // query 0
            const float dx = x - qx0, dy = y - qy0, dz = z - qz0;
            const bool within = dx * dx + dy * dy + dz * dz < R2;
            const unsigned long long m = __ballot(within);
            if (m) {
                if (f0 < 0) f0 = (c << 6) + __builtin_ctzll(m);
                if (within) {
                    const int slot = cnt0 + __popcll(m & below);
                    if (slot < K) op0[slot] = j;
                }
                cnt0 += __popcll(m);
            }
        }
        {   // query 1
            const float dx = x - qx1, dy = y - qy1, dz = z - qz1;
            const bool within = dx * dx + dy * dy + dz * dz < R2;
            const unsigned long long m = __ballot(within);
            if (m) {
                if (f1 < 0) f1 = (c << 6) + __builtin_ctzll(m);
                if (within) {
                    const int slot = cnt1 + __popcll(m & below);
                    if (slot < K) op1[slot] = j;
                }
                cnt1 += __popcll(m);
            }
        }
    }

    // Pad remaining slots with the first hit (0 if none) — matches the
    // reference's argmax(within) fallback exactly.
    const int first0 = (f0 < 0) ? 0 : f0;
    const int first1 = (f1 < 0) ? 0 : f1;
    const int c0 = cnt0 < K ? cnt0 : K;
    const int c1 = cnt1 < K ? cnt1 : K;
    if (c0 + lane < K) op0[c0 + lane] = first0;
    if (c1 + lane < K) op1[c1 + lane] = first1;
}

extern "C" void kernel_launch(void* const* d_in, const int* in_sizes, int n_in,
                              void* d_out, int out_size, void* d_ws, size_t ws_size,
                              hipStream_t stream) {
    const float* query = (const float*)d_in[0];   // B*N1*3 floats
    const float* key   = (const float*)d_in[1];   // B*N2*3 floats
    int* out = (int*)d_out;                       // B*N1*K int32
    (void)d_ws; (void)ws_size;                    // no workspace needed

    // 8192 queries / (4 waves x 2 queries) per 256-thread block.
    bq_brute2_kernel<<<(B * N1) / 8, 256, 0, stream>>>(query, key, out);
}

// Round 5
// 72.497 us; speedup vs baseline: 1.3264x; 1.3264x over previous
//
#include <hip/hip_runtime.h>

// Ball query via 5x5x5 uniform grid + per-batch counting sort + per-wave hit
// bitmap. B=4, N1=2048 queries, N2=8192 keys, K=64, r=0.1 (cell = 0.2 = 2r,
// so a query ball overlaps at most a 2x2x2 octant of cells).
//
// R5: TWO dispatches, no cross-block coordination anywhere.
//   1. build_kernel : 4 blocks (one per BATCH) x 1024 threads. Each block
//      privately: LDS-hists its batch's 8192 keys (8/thread, coalesced,
//      coords held in registers), Hillis-Steele scans 126 cells, writes
//      cell_start[b][126], scatters float4{x,y,z,idx} into sorted[b][..]
//      via LDS cursor atomics. Entirely block-local => no hists[] global
//      array, no handshake, no grid sync. ~3us on 4 CUs.
//   2. ballquery_grid_kernel : verified R0 body, unchanged. One wave per
//      query; scans <=4 contiguous (x,y)-column z-runs, sets bits in an
//      8192-bit wave-private LDS bitmap keyed by ORIGINAL key index, then
//      extracts the first K set bits in order (exact key-order output even
//      when >K hits).
//
// Ledger (dur_us = ~40us ws-poison + ~4us fixed + kernels + ~5us/node):
//   R0 3-node hist/scatter/query: 68.2   <- baseline structure
//   R1 fuse-by-redundancy:        76.1   (32x redundant build work)
//   R2 cg::grid.sync:            300.2   (~120us/sync on this stack)
//   R3 agent-scope flag handshake:78.8   (L3-round-trip spin + hist reload)
//   R4 single-node brute force:   96.2   (16x the distance tests, 52us kernel)
// R5 keeps R0's work shape but needs one fewer node: scatter no longer
// depends on other blocks' histograms because the whole batch lives in one
// (1024-thread) block.

constexpr int   K    = 64;
constexpr float R2   = 0.01f;   // 0.1^2
constexpr int   B    = 4;
constexpr int   N1   = 2048;
constexpr int   N2   = 8192;
constexpr int   GC   = 5;                 // grid cells per dim
constexpr int   NCELL = GC * GC * GC;     // 125
constexpr float INVCELL = 5.0f;           // 1 / 0.2
constexpr int   KPT  = N2 / 1024;         // keys per build thread = 8

// ---------------- workspace layout ----------------
// [0, 512KB) : sorted float4 [B*N2]
// then       : cell_start [B*(NCELL+1)] ints
constexpr size_t SORTED_BYTES = (size_t)B * N2 * 16;
constexpr size_t CS_BYTES     = (size_t)B * (NCELL + 1) * 4;
constexpr size_t WS_NEEDED    = SORTED_BYTES + CS_BYTES;

__device__ __forceinline__ int cell_of(float v) {
    int c = (int)(v * INVCELL);
    return c < 0 ? 0 : (c > GC - 1 ? GC - 1 : c);
}

// ---------------- pass 1: per-batch block-local build ----------------
__global__ __launch_bounds__(1024) void build_kernel(
    const float* __restrict__ key,       // [B*N2, 3]
    int* __restrict__ cell_start,        // [B, NCELL+1]
    float4* __restrict__ sorted)         // [B*N2]
{
    __shared__ int h[NCELL];             // batch per-cell totals
    __shared__ int sbuf[128];            // scan buffer
    __shared__ int cursor[NCELL];        // scatter cursors

    const int b = blockIdx.x;            // batch 0..3
    const int t = threadIdx.x;           // 0..1023

    if (t < NCELL) h[t] = 0;
    __syncthreads();

    // ---- hist: 8 coalesced keys per thread, coords kept in registers ----
    const float* kb = key + (size_t)b * N2 * 3;
    float kx[KPT], ky[KPT], kz[KPT];
    int   kc[KPT];
    #pragma unroll
    for (int i = 0; i < KPT; ++i) {
        const int j = i * 1024 + t;      // 0..8191, coalesced per iter
        kx[i] = kb[j * 3 + 0];
        ky[i] = kb[j * 3 + 1];
        kz[i] = kb[j * 3 + 2];
        kc[i] = (cell_of(kx[i]) * GC + cell_of(ky[i])) * GC + cell_of(kz[i]);
        atomicAdd(&h[kc[i]], 1);
    }
    __syncthreads();

    // ---- inclusive Hillis-Steele scan of the 125 cell totals ----
    const int total = (t < NCELL) ? h[t] : 0;
    if (t < 128) sbuf[t] = total;
    __syncthreads();
    for (int off = 1; off < 128; off <<= 1) {
        int v = 0;
        if (t < 128 && t >= off) v = sbuf[t - off];
        __syncthreads();
        if (t < 128) sbuf[t] += v;
        __syncthreads();
    }
    if (t < NCELL) {
        cursor[t] = sbuf[t] - total;               // exclusive cell start
        cell_start[b * (NCELL + 1) + t + 1] = sbuf[t];
        if (t == 0) cell_start[b * (NCELL + 1)] = 0;
    }
    __syncthreads();

    // ---- scatter (within-cell order arbitrary; bitmap restores it) ----
    float4* sb = sorted + (size_t)b * N2;
    #pragma unroll
    for (int i = 0; i < KPT; ++i) {
        const int pos = atomicAdd(&cursor[kc[i]], 1);   // LDS, block-local
        float4 v;
        v.x = kx[i]; v.y = ky[i]; v.z = kz[i];
        v.w = __int_as_float(i * 1024 + t);             // original key id
        sb[pos] = v;
    }
}

// ---------------- pass 2: per-query grid scan (verified R0 body) -----------
__global__ __launch_bounds__(256) void ballquery_grid_kernel(
    const float* __restrict__ query,        // [B*N1, 3]
    const float4* __restrict__ sorted,      // [B*N2] grouped by cell
    const int* __restrict__ cell_start,     // [B, 126]
    int* __restrict__ out)                  // [B*N1, K]
{
    __shared__ unsigned int bm[4 * 256];    // 4 waves x 8192-bit bitmap

    const int lane = threadIdx.x & 63;
    const int wv   = threadIdx.x >> 6;
    const int q    = blockIdx.x * 4 + wv;   // 0 .. B*N1-1
    const int b    = q >> 11;

    const float qx = query[q * 3 + 0];
    const float qy = query[q * 3 + 1];
    const float qz = query[q * 3 + 2];

    // Octant of cells the ball can touch (cell = 2r, so +/-1 on the near side).
    const float ux = qx * INVCELL, uy = qy * INVCELL, uz = qz * INVCELL;
    const int cx = cell_of(qx), cy = cell_of(qy), cz = cell_of(qz);
    const int nx = (ux - cx < 0.5f) ? cx - 1 : cx + 1;
    const int ny = (uy - cy < 0.5f) ? cy - 1 : cy + 1;
    const int nz = (uz - cz < 0.5f) ? cz - 1 : cz + 1;
    const int xlo = max(0, min(cx, nx)), xhi = min(GC - 1, max(cx, nx));
    const int ylo = max(0, min(cy, ny)), yhi = min(GC - 1, max(cy, ny));
    const int zlo = max(0, min(cz, nz)), zhi = min(GC - 1, max(cz, nz));

    unsigned int* wbm = bm + wv * 256;
    uint4 zz; zz.x = zz.y = zz.z = zz.w = 0u;
    ((uint4*)wbm)[lane] = zz;               // clear bitmap (ds_write_b128)

    const int*    cs = cell_start + b * (NCELL + 1);
    const float4* sb = sorted + (size_t)b * N2;

    for (int xx = xlo; xx <= xhi; ++xx) {
        for (int yy = ylo; yy <= yhi; ++yy) {
            const int colz = (xx * GC + yy) * GC;
            const int s = cs[colz + zlo];
            const int e = cs[colz + zhi + 1];          // z-cells are contiguous
            for (int t0 = s; t0 < e; t0 += 64) {
                const int i = t0 + lane;
                const float4 kv = sb[min(i, e - 1)];
                const float dx = kv.x - qx;
                const float dy = kv.y - qy;
                const float dz = kv.z - qz;
                const bool within = (i < e) && (dx * dx + dy * dy + dz * dz < R2);
                if (within) {
                    const int id = __float_as_int(kv.w);
                    atomicOr(&wbm[id >> 5], 1u << (id & 31));
                }
            }
        }
    }

    // ---- extraction: lane owns original-index range [128*lane, 128*lane+128)
    const uint4 w = ((const uint4*)wbm)[lane];
    const int c = __popc(w.x) + __popc(w.y) + __popc(w.z) + __popc(w.w);

    // inclusive wave prefix sum of c
    int x = c;
    #pragma unroll
    for (int off = 1; off < 64; off <<= 1) {
        int y = __shfl_up(x, off);
        if (lane >= off) x += y;
    }
    const int base = x - c;
    const int cnt  = __shfl(x, 63);

    // first set bit overall (0 if none)
    int fs;
    if      (w.x) fs = __builtin_ctz(w.x);
    else if (w.y) fs = 32 + __builtin_ctz(w.y);
    else if (w.z) fs = 64 + __builtin_ctz(w.z);
    else if (w.w) fs = 96 + __builtin_ctz(w.w);
    else          fs = 0;
    int myfirst = c ? (lane << 7) + fs : 0x7fffffff;
    #pragma unroll
    for (int off = 32; off; off >>= 1)
        myfirst = min(myfirst, __shfl_xor(myfirst, off));
    const int firstIdx = (cnt == 0) ? 0 : myfirst;

    // emit set bits in order
    int* op = out + q * K;
    int slot = base;
    unsigned int wr[4] = {w.x, w.y, w.z, w.w};
    #pragma unroll
    for (int r = 0; r < 4; ++r) {
        unsigned int m = wr[r];
        const int bb = (lane << 7) + (r << 5);
        while (m) {
            const int bp = __builtin_ctz(m);
            m &= m - 1;
            if (slot < K) op[slot] = bb + bp;
            ++slot;
        }
    }

    // pad remaining slots with firstIdx
    const int kpad = cnt < K ? cnt : K;
    const int s2 = kpad + lane;
    if (s2 < K) op[s2] = firstIdx;
}

// ---------------- fallback (ws too small): brute force (R4-verified) -------
__global__ __launch_bounds__(256) void bq_brute2_kernel(
    const float* __restrict__ query, const float* __restrict__ key,
    int* __restrict__ out)
{
    const int lane = threadIdx.x & 63;
    const int w    = blockIdx.x * 4 + (threadIdx.x >> 6);
    const int q0   = w * 2;
    const int q1   = q0 + 1;
    const int b    = q0 >> 11;

    const float qx0 = query[q0 * 3 + 0], qy0 = query[q0 * 3 + 1], qz0 = query[q0 * 3 + 2];
    const float qx1 = query[q1 * 3 + 0], qy1 = query[q1 * 3 + 1], qz1 = query[q1 * 3 + 2];

    const float* kb = key + (size_t)b * N2 * 3;
    const unsigned long long below = (lane == 0) ? 0ull : (~0ull >> (64 - lane));

    int cnt0 = 0, cnt1 = 0, f0 = -1, f1 = -1;
    int* op0 = out + (size_t)q0 * K;
    int* op1 = out + (size_t)q1 * K;

    #pragma unroll 4
    for (int c = 0; c < N2 / 64; ++c) {
        const int j = (c << 6) + lane;
        const float x = kb[j * 3 + 0];
        const float y = kb[j * 3 + 1];
        const float z = kb[j * 3 + 2];
        {
            const float dx = x - qx0, dy = y - qy0, dz = z - qz0;
            const bool within = dx * dx + dy * dy + dz * dz < R2;
            const unsigned long long m = __ballot(within);
            if (m) {
                if (f0 < 0) f0 = (c << 6) + __builtin_ctzll(m);
                if (within) {
                    const int slot = cnt0 + __popcll(m & below);
                    if (slot < K) op0[slot] = j;
                }
                cnt0 += __popcll(m);
            }
        }
        {
            const float dx = x - qx1, dy = y - qy1, dz = z - qz1;
            const bool within = dx * dx + dy * dy + dz * dz < R2;
            const unsigned long long m = __ballot(within);
            if (m) {
                if (f1 < 0) f1 = (c << 6) + __builtin_ctzll(m);
                if (within) {
                    const int slot = cnt1 + __popcll(m & below);
                    if (slot < K) op1[slot] = j;
                }
                cnt1 += __popcll(m);
            }
        }
    }

    const int first0 = (f0 < 0) ? 0 : f0;
    const int first1 = (f1 < 0) ? 0 : f1;
    const int c0 = cnt0 < K ? cnt0 : K;
    const int c1 = cnt1 < K ? cnt1 : K;
    if (c0 + lane < K) op0[c0 + lane] = first0;
    if (c1 + lane < K) op1[c1 + lane] = first1;
}

extern "C" void kernel_launch(void* const* d_in, const int* in_sizes, int n_in,
                              void* d_out, int out_size, void* d_ws, size_t ws_size,
                              hipStream_t stream) {
    const float* query = (const float*)d_in[0];   // B*N1*3 floats
    const float* key   = (const float*)d_in[1];   // B*N2*3 floats
    int* out = (int*)d_out;                       // B*N1*K int32

    if (ws_size < WS_NEEDED) {
        bq_brute2_kernel<<<(B * N1) / 8, 256, 0, stream>>>(query, key, out);
        return;
    }

    float4* sorted     = (float4*)d_ws;
    int*    cell_start = (int*)((char*)d_ws + SORTED_BYTES);

    build_kernel<<<B, 1024, 0, stream>>>(key, cell_start, sorted);
    ballquery_grid_kernel<<<(B * N1) / 4, 256, 0, stream>>>(query, sorted, cell_start, out);
}